// Round 1
// 66.349 us; speedup vs baseline: 1.0454x; 1.0454x over previous
//
#include <hip/hip_runtime.h>

#define KE_CONST 332.0636f
constexpr int TILE = 256;   // max particles per frame handled in fast path
constexpr int NT   = 1024;  // threads per block (16 waves)
constexpr int NW   = NT / 64;

__global__ __launch_bounds__(NT) void lj_coul_frame_kernel(
    const float* __restrict__ pos, const float* __restrict__ charges,
    const float* __restrict__ lj, const int* __restrict__ frames,
    const int* __restrict__ mols, float* __restrict__ out, int N)
{
    const int f = blockIdx.x;
    const int tid = threadIdx.x;
    const int lane = tid & 63;
    const int wv = tid >> 6;

    __shared__ float jx[TILE], jy[TILE], jz[TILE], jq[TILE], jsig[TILE], jse[TILE];
    __shared__ int   jmol[TILE];
    __shared__ int   spack[NW];
    __shared__ float wsum[NW];

    // --- cooperative frame-range find: packed count (lo in low16, hi in high16) ---
    int pack = 0;
    {
        const int N4 = N >> 2;
        const int4* f4 = (const int4*)frames;
        for (int k = tid; k < N4; k += NT) {
            const int4 v = f4[k];
            pack += (v.x <  f) + (v.y <  f) + (v.z <  f) + (v.w <  f);
            pack += ((v.x <= f) + (v.y <= f) + (v.z <= f) + (v.w <= f)) << 16;
        }
        for (int k = (N4 << 2) + tid; k < N; k += NT) {
            const int v = frames[k];
            pack += (v < f) + ((v <= f) << 16);
        }
        for (int off = 32; off > 0; off >>= 1)
            pack += __shfl_down(pack, off, 64);
        if (lane == 0) spack[wv] = pack;
        __syncthreads();
    }
    int tot = 0;
    #pragma unroll
    for (int w = 0; w < NW; ++w) tot += spack[w];
    const int lo = tot & 0xFFFF;
    const int hi = tot >> 16;
    const int nf = hi - lo;

    float acc = 0.0f;

    if (nf <= TILE) {
        // --- fast path: whole frame fits one tile; i-data comes from LDS ---
        for (int t = tid; t < nf; t += NT) {
            const int j = lo + t;
            jx[t]   = pos[3 * j + 0];
            jy[t]   = pos[3 * j + 1];
            jz[t]   = pos[3 * j + 2];
            jq[t]   = charges[j];
            jsig[t] = lj[2 * j + 0];
            jse[t]  = sqrtf(lj[2 * j + 1]);   // sqrt(eps): sqrt(ei*ej) = sqrt(ei)*sqrt(ej)
            jmol[t] = mols[j];
        }
        __syncthreads();

        for (int ti = lane; ti < nf; ti += 64) {
            const float xi  = jx[ti];
            const float yi  = jy[ti];
            const float zi  = jz[ti];
            const float ci  = KE_CONST * jq[ti];
            const float si  = jsig[ti];
            const float sei = jse[ti];
            const int   mi  = jmol[ti];

            for (int t = wv; t < nf; t += NW) {   // wave-uniform t -> LDS broadcast
                const float dx = xi - jx[t];
                const float dy = yi - jy[t];
                const float dz = zi - jz[t];
                const float r2 = dx * dx + dy * dy + dz * dz;
                const float inv_r  = rsqrtf(r2);
                const float inv_r2 = inv_r * inv_r;
                const float coul = ci * jq[t] * inv_r;
                const float s    = si + jsig[t];
                const float sr2  = 0.25f * s * s * inv_r2;
                const float sr6  = sr2 * sr2 * sr2;
                const float ljv  = 4.0f * (sei * jse[t]) * (sr6 * sr6 - sr6);
                acc += (mi != jmol[t]) ? (coul + ljv) : 0.0f;
            }
        }
    } else {
        // --- general path: multi-tile (not expected for these inputs) ---
        for (int jt = lo; jt < hi; jt += TILE) {
            const int cnt = min(TILE, hi - jt);
            for (int t = tid; t < cnt; t += NT) {
                const int j = jt + t;
                jx[t]   = pos[3 * j + 0];
                jy[t]   = pos[3 * j + 1];
                jz[t]   = pos[3 * j + 2];
                jq[t]   = charges[j];
                jsig[t] = lj[2 * j + 0];
                jse[t]  = sqrtf(lj[2 * j + 1]);
                jmol[t] = mols[j];
            }
            __syncthreads();

            for (int i = lo + lane; i < hi; i += 64) {
                const float xi  = pos[3 * i + 0];
                const float yi  = pos[3 * i + 1];
                const float zi  = pos[3 * i + 2];
                const float ci  = KE_CONST * charges[i];
                const float si  = lj[2 * i + 0];
                const float sei = sqrtf(lj[2 * i + 1]);
                const int   mi  = mols[i];

                for (int t = wv; t < cnt; t += NW) {
                    const float dx = xi - jx[t];
                    const float dy = yi - jy[t];
                    const float dz = zi - jz[t];
                    const float r2 = dx * dx + dy * dy + dz * dz;
                    const float inv_r  = rsqrtf(r2);
                    const float inv_r2 = inv_r * inv_r;
                    const float coul = ci * jq[t] * inv_r;
                    const float s    = si + jsig[t];
                    const float sr2  = 0.25f * s * s * inv_r2;
                    const float sr6  = sr2 * sr2 * sr2;
                    const float ljv  = 4.0f * (sei * jse[t]) * (sr6 * sr6 - sr6);
                    acc += (mi != jmol[t]) ? (coul + ljv) : 0.0f;
                }
            }
            __syncthreads();
        }
    }

    // wave (64-lane) shuffle reduction, then cross-wave via LDS
    for (int off = 32; off > 0; off >>= 1)
        acc += __shfl_down(acc, off, 64);
    if (lane == 0) wsum[wv] = acc;
    __syncthreads();
    if (tid == 0) {
        float s = 0.0f;
        #pragma unroll
        for (int w = 0; w < NW; ++w) s += wsum[w];
        out[f] = s;
    }
}

extern "C" void kernel_launch(void* const* d_in, const int* in_sizes, int n_in,
                              void* d_out, int out_size, void* d_ws, size_t ws_size,
                              hipStream_t stream) {
    const float* pos     = (const float*)d_in[0];
    const float* charges = (const float*)d_in[1];
    const float* lj      = (const float*)d_in[2];
    const int*   frames  = (const int*)d_in[3];
    const int*   mols    = (const int*)d_in[4];
    const int    N       = in_sizes[3];   // element count of frames array
    const int    F       = out_size;      // one output per frame

    lj_coul_frame_kernel<<<F, NT, 0, stream>>>(pos, charges, lj, frames, mols,
                                               (float*)d_out, N);
}